// Round 3
// baseline (5992.302 us; speedup 1.0000x reference)
//
#include <hip/hip_runtime.h>
#include <math.h>

#define NV 10000
#define B 512
#define L 256
#define E 64

typedef _Float16 f16;
typedef _Float16 f16x8 __attribute__((ext_vector_type(8)));
typedef float f32x4 __attribute__((ext_vector_type(4)));

// ws layout (f32 offsets)
#define OFF_WIHT   0u         // [256][1024] fp32: WihT[k*1024+r] = W_ih[r*256+k]
#define OFF_WA1HT  262144u    // [256][256]
#define OFF_WA1NT  327680u    // [256][256]
#define OFF_WC1T   393216u    // [256][256]
#define OFF_WB     458752u    // 262144 f16 (131072 f32 slots): MFMA B-frags of W_hh
#define OFF_EXCH   589824u    // 131072 u32: [par2][g64][r4][word256] h-slice exchange
#define OFF_FLAGS  720896u    // 256 int
#define OFF_PEMB   721920u    // [10000][1024] f32: graph_emb @ W_ih^T + (b_ih+b_hh)
#define OFF_AEMB   10961920u  // [10000][256] f16: graph_emb @ Wa1n^T
#define OFF_HBUF   12241920u  // [512][256] f32 h_final
// total 12,372,992 f32 = 49.5 MB

__global__ __launch_bounds__(256) void k_prep(
    const float* __restrict__ W_ih, const float* __restrict__ W_hh,
    const float* __restrict__ Wa1, const float* __restrict__ Wc1,
    float* __restrict__ ws) {
  int idx = blockIdx.x * 256 + threadIdx.x;
  if (idx < 262144) {  // W_ih transpose (for k_pemb)
    int k = idx >> 10, r = idx & 1023;
    ws[OFF_WIHT + idx] = W_ih[r * 256 + k];
    return;
  }
  int p2 = idx - 262144;
  if (p2 < 262144) {  // W_hh as f16 MFMA B-fragments
    int j = p2 & 7, lane = (p2 >> 3) & 63, kt = (p2 >> 9) & 7;
    int nt = (p2 >> 12) & 15, r = (p2 >> 16) & 3;
    int n = (nt >> 2) * 256 + r * 64 + (nt & 3) * 16 + (lane & 15);
    int k = kt * 32 + ((lane >> 4) & 3) * 8 + j;
    ((f16*)(ws + OFF_WB))[p2] = (f16)W_hh[n * 256 + k];
    return;
  }
  int p3 = p2 - 262144;
  if (p3 < 65536) {  // actor/critic transposes
    int k = p3 >> 8, j = p3 & 255;
    ws[OFF_WA1HT + p3] = Wa1[j * 512 + k];
    ws[OFF_WA1NT + p3] = Wa1[j * 512 + 256 + k];
    ws[OFF_WC1T + p3] = Wc1[j * 256 + k];
    return;
  }
  int p4 = p3 - 65536;
  if (p4 < 256) ((int*)(ws + OFF_FLAGS))[p4] = 0;
}

// P_emb[v][col] = sum_k graph_emb[v,k]*W_ih[col,k] + b_ih[col]+b_hh[col]
__global__ __launch_bounds__(1024) void k_pemb(
    const float* __restrict__ ge, const float* __restrict__ b_ih,
    const float* __restrict__ b_hh, float* __restrict__ ws) {
  __shared__ float X[16][256];
  const float* __restrict__ WihT = ws + OFF_WIHT;
  float* __restrict__ P = ws + OFF_PEMB;
  const int vbase = blockIdx.x * 16;
  const int tid = threadIdx.x;
  for (int i = tid; i < 16 * 256; i += 1024)
    X[i >> 8][i & 255] = ge[(vbase + (i >> 8)) * 256 + (i & 255)];
  __syncthreads();
  float acc[16];
#pragma unroll
  for (int v = 0; v < 16; ++v) acc[v] = 0.f;
  const int col = tid;
  for (int k = 0; k < 256; ++k) {
    float w = WihT[k * 1024 + col];
#pragma unroll
    for (int v = 0; v < 16; ++v) acc[v] += w * X[v][k];
  }
  const float bias = b_ih[col] + b_hh[col];
#pragma unroll
  for (int v = 0; v < 16; ++v)
    P[(size_t)(vbase + v) * 1024 + col] = acc[v] + bias;
}

// A_emb[v][j] = sum_k graph_emb[v,k]*Wa1[j,256+k]  (stored f16)
__global__ __launch_bounds__(256) void k_aemb(
    const float* __restrict__ ge, float* __restrict__ ws) {
  __shared__ float X[16][256];
  const float* __restrict__ WnT = ws + OFF_WA1NT;
  f16* __restrict__ A = (f16*)(ws + OFF_AEMB);
  const int vbase = blockIdx.x * 16;
  const int tid = threadIdx.x;
  for (int i = tid; i < 16 * 256; i += 256)
    X[i >> 8][i & 255] = ge[(vbase + (i >> 8)) * 256 + (i & 255)];
  __syncthreads();
  float acc[16];
#pragma unroll
  for (int v = 0; v < 16; ++v) acc[v] = 0.f;
  for (int k = 0; k < 256; ++k) {
    float w = WnT[k * 256 + tid];
#pragma unroll
    for (int v = 0; v < 16; ++v) acc[v] += w * X[v][k];
  }
#pragma unroll
  for (int v = 0; v < 16; ++v)
    A[(size_t)(vbase + v) * 256 + tid] = (f16)acc[v];
}

// LSTM: 64 groups x (R=4 blocks) x (G=8 paths). W_hh persistent in VGPRs.
// Block r of group g owns gate-cols {gate*256 + r*64 + 0..63 : gate in i,f,g,o}.
__global__ __launch_bounds__(256) void k_lstm(
    const int* __restrict__ paths, const int* __restrict__ path_lens,
    float* __restrict__ ws) {
  const int blk = blockIdx.x;
  const int x = blk & 7, i5 = blk >> 3;
  const int g = x * 8 + (i5 >> 2);  // same-XCD grouping heuristic (perf only)
  const int r = i5 & 3;
  const int tid = threadIdx.x;
  const int wave = tid >> 6, lane = tid & 63;
  const int l15 = lane & 15, quad = lane >> 4;

  __shared__ f16 hA[16 * 280];      // A matrix [m=16][k=256], row stride 280
  __shared__ float gbuf[8 * 256];   // gates [path][gate*64+hc]
  __shared__ float pbuf[8 * 260];   // staged P rows (block's 256 cols)
  __shared__ int vbuf[8];
  __shared__ int lens[8];
  __shared__ int lmax_s;

  for (int i = tid; i < 16 * 280 / 2; i += 256) ((unsigned int*)hA)[i] = 0;
  if (tid < 8) {
    lens[tid] = path_lens[g * 8 + tid];
    vbuf[tid] = paths[(g * 8 + tid) * L];
  }
  __syncthreads();
  if (tid == 0) {
    int m = lens[0];
    for (int p = 1; p < 8; ++p) m = max(m, lens[p]);
    lmax_s = m;
  }
  __syncthreads();
  const int lmax = lmax_s;

  // persistent B fragments: wave w holds n-tiles nt = w*4+q (q=0..3), kt=0..7
  const f16* __restrict__ WB = (const f16*)(ws + OFF_WB);
  f16x8 Bf[4][8];
#pragma unroll
  for (int q = 0; q < 4; ++q)
#pragma unroll
    for (int kt = 0; kt < 8; ++kt) {
      const int nt = wave * 4 + q;
      Bf[q][kt] = *(const f16x8*)(WB + (size_t)(((r * 16 + nt) * 8 + kt) * 64 + lane) * 8);
    }
  // identity A-fragment for the P-injection k-tile (A[m][256+m]=1, m<16)
  f16x8 Aid;
#pragma unroll
  for (int j = 0; j < 8; ++j) Aid[j] = (f16)((quad * 8 + j == l15) ? 1.0f : 0.0f);

  // cell state: thread owns (path cp, h-cols r*64+sc, +1)
  const int cp = tid >> 5;
  const int sc = (tid & 31) * 2;
  float c0 = 0.f, c1 = 0.f, h0 = 0.f, h1 = 0.f;

  const float* __restrict__ P = ws + OFF_PEMB;
  unsigned int* __restrict__ exch = (unsigned int*)(ws + OFF_EXCH);
  int* __restrict__ flags = (int*)(ws + OFF_FLAGS) + g * 4;
  const int gcol = (tid >> 6) * 256 + r * 64 + (tid & 63);  // global P col for this thread

  for (int t = 0; t < lmax; ++t) {
    // P-row gather (issued early; coalesced 64-wide per path)
    float pv[8];
#pragma unroll
    for (int p = 0; p < 8; ++p)
      pv[p] = P[(size_t)vbuf[p] * 1024 + gcol];
    // A fragments from LDS
    f16x8 Af[8];
#pragma unroll
    for (int kt = 0; kt < 8; ++kt)
      Af[kt] = *(const f16x8*)(hA + 280 * l15 + kt * 32 + quad * 8);
    // MFMA over k
    f32x4 C[4];
#pragma unroll
    for (int q = 0; q < 4; ++q) {
      f32x4 acc = {0.f, 0.f, 0.f, 0.f};
#pragma unroll
      for (int kt = 0; kt < 8; ++kt)
        acc = __builtin_amdgcn_mfma_f32_16x16x32_f16(Af[kt], Bf[q][kt], acc, 0, 0, 0);
      C[q] = acc;
    }
    // stage P rows to LDS
#pragma unroll
    for (int p = 0; p < 8; ++p) pbuf[p * 260 + tid] = pv[p];
    __syncthreads();
    // P-injection k-tile + dump gates
#pragma unroll
    for (int q = 0; q < 4; ++q) {
      const int nt = wave * 4 + q;
      f16x8 Pf;
#pragma unroll
      for (int j = 0; j < 8; ++j) Pf[j] = (f16)0.f;
      if (quad == 0) {
#pragma unroll
        for (int j = 0; j < 8; ++j) Pf[j] = (f16)pbuf[j * 260 + nt * 16 + l15];
      }
      f32x4 acc = __builtin_amdgcn_mfma_f32_16x16x32_f16(Aid, Pf, C[q], 0, 0, 0);
      if (lane < 32) {
#pragma unroll
        for (int reg = 0; reg < 4; ++reg) {
          int p = quad * 4 + reg;  // 0..7
          gbuf[p * 256 + wave * 64 + q * 16 + l15] = acc[reg];
        }
      }
    }
    __syncthreads();
    // cell update (f32)
    {
      const float* gb = gbuf + cp * 256;
      const float gi0 = gb[sc],       gi1 = gb[sc + 1];
      const float gf0 = gb[64 + sc],  gf1 = gb[64 + sc + 1];
      const float gg0 = gb[128 + sc], gg1 = gb[128 + sc + 1];
      const float go0 = gb[192 + sc], go1 = gb[192 + sc + 1];
      if (t < lens[cp]) {
        const float si0 = 1.f / (1.f + expf(-gi0)), si1 = 1.f / (1.f + expf(-gi1));
        const float sf0 = 1.f / (1.f + expf(-gf0)), sf1 = 1.f / (1.f + expf(-gf1));
        const float so0 = 1.f / (1.f + expf(-go0)), so1 = 1.f / (1.f + expf(-go1));
        c0 = sf0 * c0 + si0 * tanhf(gg0);
        c1 = sf1 * c1 + si1 * tanhf(gg1);
        h0 = so0 * tanhf(c0);
        h1 = so1 * tanhf(c1);
      }
      union { f16 h2[2]; unsigned int u; } pk;
      pk.h2[0] = (f16)h0; pk.h2[1] = (f16)h1;
      *(unsigned int*)(hA + cp * 280 + r * 64 + sc) = pk.u;  // own slice
      exch[(((t & 1) * 64 + g) * 4 + r) * 256 + tid] = pk.u; // publish
      if (tid < 8) vbuf[tid] = paths[(g * 8 + tid) * L + min(t + 1, L - 1)];
    }
    __threadfence();
    __syncthreads();
    if (tid == 0)
      __hip_atomic_store(&flags[r], t + 1, __ATOMIC_RELEASE, __HIP_MEMORY_SCOPE_AGENT);
    __syncthreads();
    if (tid < 3) {
      const int rr = (r + 1 + tid) & 3;
      while (__hip_atomic_load(&flags[rr], __ATOMIC_ACQUIRE, __HIP_MEMORY_SCOPE_AGENT) < t + 1) {}
    }
    __syncthreads();
    // import the other 3 h-slices
#pragma unroll
    for (int s = 0; s < 3; ++s) {
      const int rr = (r + 1 + s) & 3;
      unsigned int w = __hip_atomic_load(&exch[(((t & 1) * 64 + g) * 4 + rr) * 256 + tid],
                                         __ATOMIC_RELAXED, __HIP_MEMORY_SCOPE_AGENT);
      *(unsigned int*)(hA + cp * 280 + rr * 64 + sc) = w;
    }
    __syncthreads();
  }

  float* __restrict__ hbuf = ws + OFF_HBUF;
  hbuf[(g * 8 + cp) * 256 + r * 64 + sc] = h0;
  hbuf[(g * 8 + cp) * 256 + r * 64 + sc + 1] = h1;
}

// critic head: one block per path
__global__ __launch_bounds__(256) void k_critic(
    const float* __restrict__ bc1, const float* __restrict__ Wc2,
    const float* __restrict__ bc2, float* __restrict__ out,
    const float* __restrict__ ws) {
  __shared__ float hs[256];
  __shared__ float red[256];
  const float* __restrict__ Wc1T = ws + OFF_WC1T;
  const float* __restrict__ hbuf = ws + OFF_HBUF;
  const int b = blockIdx.x, j = threadIdx.x;
  hs[j] = hbuf[b * 256 + j];
  __syncthreads();
  float ch = bc1[j];
  for (int k = 0; k < 256; ++k) ch += Wc1T[k * 256 + j] * hs[k];
  ch = ch > 0.f ? ch : expm1f(ch);
  red[j] = ch * Wc2[j];
  __syncthreads();
  for (int s = 128; s > 0; s >>= 1) {
    if (j < s) red[j] += red[j + s];
    __syncthreads();
  }
  if (j == 0) out[B * E + b] = red[0] + bc2[0];
}

// actor head + masked softmax: one block per path
__global__ __launch_bounds__(256) void k_actor(
    const int* __restrict__ neighbors, const int* __restrict__ n_nb,
    const float* __restrict__ ba1, const float* __restrict__ Wa2,
    const float* __restrict__ ba2, float* __restrict__ out,
    const float* __restrict__ ws) {
  __shared__ float hs[256];
  __shared__ float u[256];
  __shared__ float logits[64];
  const float* __restrict__ Wa1hT = ws + OFF_WA1HT;
  const f16* __restrict__ A = (const f16*)(ws + OFF_AEMB);
  const float* __restrict__ hbuf = ws + OFF_HBUF;
  const int b = blockIdx.x;
  const int j = threadIdx.x;
  hs[j] = hbuf[b * 256 + j];
  __syncthreads();
  float acc = ba1[j];
  for (int k = 0; k < 256; ++k) acc += Wa1hT[k * 256 + j] * hs[k];
  u[j] = acc;
  __syncthreads();
  const int wave = j >> 6, lane = j & 63;
  const float ba2v = ba2[0];
  for (int e = wave; e < 64; e += 4) {
    const int v = neighbors[b * 64 + e];
    float s = 0.f;
#pragma unroll
    for (int m = 0; m < 4; ++m) {
      const int jj = lane + 64 * m;
      float a = u[jj] + (float)A[(size_t)v * 256 + jj];
      a = a > 0.f ? a : expm1f(a);
      s += a * Wa2[jj];
    }
#pragma unroll
    for (int d = 32; d > 0; d >>= 1) s += __shfl_xor(s, d, 64);
    if (lane == 0) logits[e] = s + ba2v;
  }
  __syncthreads();
  if (j < 64) {
    const int ne = n_nb[b];
    const bool valid = j < ne;
    float le = valid ? logits[j] : -1e30f;
    float m = le;
#pragma unroll
    for (int d = 32; d > 0; d >>= 1) m = fmaxf(m, __shfl_xor(m, d, 64));
    float p = valid ? expf(le - m) : 0.f;
    float sm = p;
#pragma unroll
    for (int d = 32; d > 0; d >>= 1) sm += __shfl_xor(sm, d, 64);
    out[b * 64 + j] = p / sm;
  }
}

extern "C" void kernel_launch(void* const* d_in, const int* in_sizes, int n_in,
                              void* d_out, int out_size, void* d_ws, size_t ws_size,
                              hipStream_t stream) {
  (void)in_sizes; (void)n_in; (void)out_size; (void)ws_size;
  const float* graph_emb = (const float*)d_in[0];
  const int* paths       = (const int*)d_in[1];
  const int* path_lens   = (const int*)d_in[2];
  const int* neighbors   = (const int*)d_in[3];
  const int* n_nb        = (const int*)d_in[4];
  const float* W_ih = (const float*)d_in[5];
  const float* W_hh = (const float*)d_in[6];
  const float* b_ih = (const float*)d_in[7];
  const float* b_hh = (const float*)d_in[8];
  const float* Wa1  = (const float*)d_in[9];
  const float* ba1  = (const float*)d_in[10];
  const float* Wa2  = (const float*)d_in[11];
  const float* ba2  = (const float*)d_in[12];
  const float* Wc1  = (const float*)d_in[13];
  const float* bc1  = (const float*)d_in[14];
  const float* Wc2  = (const float*)d_in[15];
  const float* bc2  = (const float*)d_in[16];
  float* out = (float*)d_out;
  float* ws = (float*)d_ws;

  hipLaunchKernelGGL(k_prep, dim3(2306), dim3(256), 0, stream, W_ih, W_hh, Wa1, Wc1, ws);
  hipLaunchKernelGGL(k_pemb, dim3(625), dim3(1024), 0, stream, graph_emb, b_ih, b_hh, ws);
  hipLaunchKernelGGL(k_aemb, dim3(625), dim3(256), 0, stream, graph_emb, ws);
  hipLaunchKernelGGL(k_lstm, dim3(256), dim3(256), 0, stream, paths, path_lens, ws);
  hipLaunchKernelGGL(k_critic, dim3(512), dim3(256), 0, stream, bc1, Wc2, bc2, out, ws);
  hipLaunchKernelGGL(k_actor, dim3(512), dim3(256), 0, stream, neighbors, n_nb, ba1, Wa2, ba2, out, ws);
}

// Round 4
// 1165.504 us; speedup vs baseline: 5.1414x; 5.1414x over previous
//
#include <hip/hip_runtime.h>
#include <math.h>

#define NV 10000
#define B 512
#define L 256
#define E 64

typedef float f32x4 __attribute__((ext_vector_type(4)));
typedef _Float16 f16;

// ws layout (f32 offsets)
#define OFF_WIHT   0u         // [256][1024] f32 W_ih^T (k_pemb)
#define OFF_WA1HT  262144u    // [256][256] f32
#define OFF_WA1NT  327680u    // [256][256] f32
#define OFF_WC1T   393216u    // [256][256] f32
#define OFF_WB     458752u    // 262144 bytes: fp8 MFMA B-frags of 8*W_hh
#define OFF_PEMB   524288u    // [10000][1024] f16: 128*(graph_emb @ W_ih^T + b)
#define OFF_AEMB   5644288u   // [10000][256] f16: graph_emb @ Wa1n^T
#define OFF_HBUF   6924288u   // [512][256] f32 h_final
// total 7,055,360 f32 = 28.2 MB

__device__ __forceinline__ int fp8_byte(float x) {
  return __builtin_amdgcn_cvt_pk_fp8_f32(x, x, 0, false) & 0xFF;
}
__device__ __forceinline__ float fp8_dec(int b) {
  return __builtin_amdgcn_cvt_f32_fp8(b, 0);
}

__global__ __launch_bounds__(256) void k_prep(
    const float* __restrict__ W_ih, const float* __restrict__ W_hh,
    const float* __restrict__ Wa1, const float* __restrict__ Wc1,
    float* __restrict__ ws) {
  int idx = blockIdx.x * 256 + threadIdx.x;
  if (idx < 262144) {  // W_ih^T for k_pemb
    int k = idx >> 10, r = idx & 1023;
    ws[OFF_WIHT + idx] = W_ih[r * 256 + k];
    return;
  }
  int p2 = idx - 262144;
  if (p2 < 262144) {  // fp8 B-frags of 8*W_hh: [(w*8+q)*8+kt][lane][j]
    int j = p2 & 7, lane = (p2 >> 3) & 63, kt = (p2 >> 9) & 7;
    int q = (p2 >> 12) & 7, w = (p2 >> 15) & 7;
    int n = (w + 8 * q) * 16 + (lane & 15);        // gate-col
    int k = kt * 32 + ((lane >> 4) & 3) * 8 + j;   // hidden idx
    ((unsigned char*)(ws + OFF_WB))[p2] = (unsigned char)fp8_byte(W_hh[n * 256 + k] * 8.f);
    return;
  }
  int i2 = p2 - 262144;
  if (i2 < 65536) {  // actor/critic transposes
    int k = i2 >> 8, j = i2 & 255;
    ws[OFF_WA1HT + i2] = Wa1[j * 512 + k];
    ws[OFF_WA1NT + i2] = Wa1[j * 512 + 256 + k];
    ws[OFF_WC1T + i2] = Wc1[j * 256 + k];
  }
}

// Pf16[v][col] = 128*(sum_k ge[v,k]*W_ih[col,k] + b_ih[col]+b_hh[col])
__global__ __launch_bounds__(1024) void k_pemb(
    const float* __restrict__ ge, const float* __restrict__ b_ih,
    const float* __restrict__ b_hh, float* __restrict__ ws) {
  __shared__ float X[16][256];
  const float* __restrict__ WihT = ws + OFF_WIHT;
  f16* __restrict__ P = (f16*)(ws + OFF_PEMB);
  const int vbase = blockIdx.x * 16;
  const int tid = threadIdx.x;
  for (int i = tid; i < 16 * 256; i += 1024)
    X[i >> 8][i & 255] = ge[(vbase + (i >> 8)) * 256 + (i & 255)];
  __syncthreads();
  float acc[16];
#pragma unroll
  for (int v = 0; v < 16; ++v) acc[v] = 0.f;
  const int col = tid;
  for (int k = 0; k < 256; ++k) {
    float w = WihT[k * 1024 + col];
#pragma unroll
    for (int v = 0; v < 16; ++v) acc[v] += w * X[v][k];
  }
  const float bias = b_ih[col] + b_hh[col];
#pragma unroll
  for (int v = 0; v < 16; ++v)
    P[(size_t)(vbase + v) * 1024 + col] = (f16)(128.f * (acc[v] + bias));
}

// A_emb[v][j] = sum_k ge[v,k]*Wa1[j,256+k]  (f16)
__global__ __launch_bounds__(256) void k_aemb(
    const float* __restrict__ ge, float* __restrict__ ws) {
  __shared__ float X[16][256];
  const float* __restrict__ WnT = ws + OFF_WA1NT;
  f16* __restrict__ A = (f16*)(ws + OFF_AEMB);
  const int vbase = blockIdx.x * 16;
  const int tid = threadIdx.x;
  for (int i = tid; i < 16 * 256; i += 256)
    X[i >> 8][i & 255] = ge[(vbase + (i >> 8)) * 256 + (i & 255)];
  __syncthreads();
  float acc[16];
#pragma unroll
  for (int v = 0; v < 16; ++v) acc[v] = 0.f;
  for (int k = 0; k < 256; ++k) {
    float w = WnT[k * 256 + tid];
#pragma unroll
    for (int v = 0; v < 16; ++v) acc[v] += w * X[v][k];
  }
#pragma unroll
  for (int v = 0; v < 16; ++v)
    A[(size_t)(vbase + v) * 256 + tid] = (f16)acc[v];
}

// LSTM: 32 blocks x 512 threads, G=16 paths/block.
// W_hh (fp8, x8) resident in VGPRs: wave w holds n-tiles {w+8q}, all kt.
// Lane owns 4 paths (quad*4+r) x 2 h-cols (w*16+l15, +128): all 4 gates
// land in this lane's C-frags -> cell update is register-local.
__global__ __launch_bounds__(512, 2) void k_lstm(
    const int* __restrict__ paths, const int* __restrict__ path_lens,
    float* __restrict__ ws) {
  const int tid = threadIdx.x, w = tid >> 6, lane = tid & 63;
  const int l15 = lane & 15, quad = lane >> 4;
  const int g16 = blockIdx.x * 16;

  __shared__ long hAbuf[2][2][528];  // [t&1][hi/lo][16 rows x 264 bytes]
  __shared__ int red16[16];
  for (int i = tid; i < 2 * 2 * 528; i += 512) ((long*)hAbuf)[i] = 0;
  if (tid < 16) red16[tid] = path_lens[g16 + tid];
  __syncthreads();
  int lmax = 0;
#pragma unroll
  for (int i = 0; i < 16; ++i) lmax = max(lmax, red16[i]);

  // persistent B-fragments (128 VGPRs)
  const long* __restrict__ WBl = (const long*)(ws + OFF_WB);
  long Bf[64];
#pragma unroll
  for (int q = 0; q < 8; ++q)
#pragma unroll
    for (int kt = 0; kt < 8; ++kt)
      Bf[q * 8 + kt] = WBl[(size_t)(((w * 8 + q) * 8 + kt) * 64 + lane)];

  const f16* __restrict__ Pf = (const f16*)(ws + OFF_PEMB);
  int qc[8];
#pragma unroll
  for (int q = 0; q < 8; ++q) qc[q] = (w + 8 * q) * 16 + l15;

  int lenr[4];
  int vcur[4];
#pragma unroll
  for (int r = 0; r < 4; ++r) {
    lenr[r] = path_lens[g16 + quad * 4 + r];
    vcur[r] = paths[(g16 + quad * 4 + r) * L];
  }
  f16 pv[8][4];
#pragma unroll
  for (int q = 0; q < 8; ++q)
#pragma unroll
    for (int r = 0; r < 4; ++r)
      pv[q][r] = Pf[(size_t)vcur[r] * 1024 + qc[q]];

  float cst[8], hst[8];
#pragma unroll
  for (int e = 0; e < 8; ++e) { cst[e] = 0.f; hst[e] = 0.f; }
  __syncthreads();

  for (int t = 0; t < lmax; ++t) {
    // C init = 128*P (prefetched)
    f32x4 Cf[8];
#pragma unroll
    for (int q = 0; q < 8; ++q)
#pragma unroll
      for (int r = 0; r < 4; ++r) Cf[q][r] = (float)pv[q][r];
    // next-step vertices (issue early)
    const int t1 = min(t + 1, L - 1);
    int vn[4];
#pragma unroll
    for (int r = 0; r < 4; ++r) vn[r] = paths[(g16 + quad * 4 + r) * L + t1];
    // MFMA: gates*128 = (16h_hi + 16h_lo)*(8W) + 128P
    const char* hAr = (const char*)hAbuf[t & 1][0];
    const char* hArl = (const char*)hAbuf[t & 1][1];
#pragma unroll
    for (int kt = 0; kt < 8; ++kt) {
      const long ah = *(const long*)(hAr + l15 * 264 + kt * 32 + quad * 8);
      const long al = *(const long*)(hArl + l15 * 264 + kt * 32 + quad * 8);
#pragma unroll
      for (int q = 0; q < 8; ++q) {
        Cf[q] = __builtin_amdgcn_mfma_f32_16x16x32_fp8_fp8(ah, Bf[q * 8 + kt], Cf[q], 0, 0, 0);
        Cf[q] = __builtin_amdgcn_mfma_f32_16x16x32_fp8_fp8(al, Bf[q * 8 + kt], Cf[q], 0, 0, 0);
      }
    }
    // prefetch next P (latency hidden by cell update)
#pragma unroll
    for (int q = 0; q < 8; ++q)
#pragma unroll
      for (int r = 0; r < 4; ++r)
        pv[q][r] = Pf[(size_t)vn[r] * 1024 + qc[q]];
    // cell update (register-local) + h write (double-buffered planes)
    char* hWh = (char*)hAbuf[(t + 1) & 1][0];
    char* hWl = (char*)hAbuf[(t + 1) & 1][1];
    const float inv = 1.f / 128.f;
#pragma unroll
    for (int half = 0; half < 2; ++half) {
#pragma unroll
      for (int r = 0; r < 4; ++r) {
        const int e = half * 4 + r;
        if (t < lenr[r]) {
          const float gi = Cf[0 + half][r] * inv, gf = Cf[2 + half][r] * inv;
          const float gg = Cf[4 + half][r] * inv, go = Cf[6 + half][r] * inv;
          const float si = __builtin_amdgcn_rcpf(1.f + __expf(-gi));
          const float sf = __builtin_amdgcn_rcpf(1.f + __expf(-gf));
          const float so = __builtin_amdgcn_rcpf(1.f + __expf(-go));
          const float tg = 1.f - 2.f * __builtin_amdgcn_rcpf(__expf(2.f * gg) + 1.f);
          const float cn = sf * cst[e] + si * tg;
          cst[e] = cn;
          hst[e] = so * (1.f - 2.f * __builtin_amdgcn_rcpf(__expf(2.f * cn) + 1.f));
        }
        const float s16 = 16.f * hst[e];
        const int hb = fp8_byte(s16);
        const int lb = fp8_byte(s16 - fp8_dec(hb));
        const int col = w * 16 + l15 + half * 128;
        const int p = quad * 4 + r;
        hWh[p * 264 + col] = (char)hb;
        hWl[p * 264 + col] = (char)lb;
      }
    }
    __syncthreads();
  }

  float* __restrict__ hbuf = ws + OFF_HBUF;
#pragma unroll
  for (int half = 0; half < 2; ++half)
#pragma unroll
    for (int r = 0; r < 4; ++r)
      hbuf[(g16 + quad * 4 + r) * 256 + w * 16 + l15 + half * 128] = hst[half * 4 + r];
}

// critic head: one block per path
__global__ __launch_bounds__(256) void k_critic(
    const float* __restrict__ bc1, const float* __restrict__ Wc2,
    const float* __restrict__ bc2, float* __restrict__ out,
    const float* __restrict__ ws) {
  __shared__ float hs[256];
  __shared__ float red[256];
  const float* __restrict__ Wc1T = ws + OFF_WC1T;
  const float* __restrict__ hbuf = ws + OFF_HBUF;
  const int b = blockIdx.x, j = threadIdx.x;
  hs[j] = hbuf[b * 256 + j];
  __syncthreads();
  float ch = bc1[j];
  for (int k = 0; k < 256; ++k) ch += Wc1T[k * 256 + j] * hs[k];
  ch = ch > 0.f ? ch : expm1f(ch);
  red[j] = ch * Wc2[j];
  __syncthreads();
  for (int s = 128; s > 0; s >>= 1) {
    if (j < s) red[j] += red[j + s];
    __syncthreads();
  }
  if (j == 0) out[B * E + b] = red[0] + bc2[0];
}

// actor head + masked softmax: one block per path
__global__ __launch_bounds__(256) void k_actor(
    const int* __restrict__ neighbors, const int* __restrict__ n_nb,
    const float* __restrict__ ba1, const float* __restrict__ Wa2,
    const float* __restrict__ ba2, float* __restrict__ out,
    const float* __restrict__ ws) {
  __shared__ float hs[256];
  __shared__ float u[256];
  __shared__ float logits[64];
  const float* __restrict__ Wa1hT = ws + OFF_WA1HT;
  const f16* __restrict__ A = (const f16*)(ws + OFF_AEMB);
  const float* __restrict__ hbuf = ws + OFF_HBUF;
  const int b = blockIdx.x;
  const int j = threadIdx.x;
  hs[j] = hbuf[b * 256 + j];
  __syncthreads();
  float acc = ba1[j];
  for (int k = 0; k < 256; ++k) acc += Wa1hT[k * 256 + j] * hs[k];
  u[j] = acc;
  __syncthreads();
  const int wave = j >> 6, lane = j & 63;
  const float ba2v = ba2[0];
  for (int e = wave; e < 64; e += 4) {
    const int v = neighbors[b * 64 + e];
    float s = 0.f;
#pragma unroll
    for (int m = 0; m < 4; ++m) {
      const int jj = lane + 64 * m;
      float a = u[jj] + (float)A[(size_t)v * 256 + jj];
      a = a > 0.f ? a : expm1f(a);
      s += a * Wa2[jj];
    }
#pragma unroll
    for (int d = 32; d > 0; d >>= 1) s += __shfl_xor(s, d, 64);
    if (lane == 0) logits[e] = s + ba2v;
  }
  __syncthreads();
  if (j < 64) {
    const int ne = n_nb[b];
    const bool valid = j < ne;
    float le = valid ? logits[j] : -1e30f;
    float m = le;
#pragma unroll
    for (int d = 32; d > 0; d >>= 1) m = fmaxf(m, __shfl_xor(m, d, 64));
    float p = valid ? expf(le - m) : 0.f;
    float sm = p;
#pragma unroll
    for (int d = 32; d > 0; d >>= 1) sm += __shfl_xor(sm, d, 64);
    out[b * 64 + j] = p / sm;
  }
}

extern "C" void kernel_launch(void* const* d_in, const int* in_sizes, int n_in,
                              void* d_out, int out_size, void* d_ws, size_t ws_size,
                              hipStream_t stream) {
  (void)in_sizes; (void)n_in; (void)out_size; (void)ws_size;
  const float* graph_emb = (const float*)d_in[0];
  const int* paths       = (const int*)d_in[1];
  const int* path_lens   = (const int*)d_in[2];
  const int* neighbors   = (const int*)d_in[3];
  const int* n_nb        = (const int*)d_in[4];
  const float* W_ih = (const float*)d_in[5];
  const float* W_hh = (const float*)d_in[6];
  const float* b_ih = (const float*)d_in[7];
  const float* b_hh = (const float*)d_in[8];
  const float* Wa1  = (const float*)d_in[9];
  const float* ba1  = (const float*)d_in[10];
  const float* Wa2  = (const float*)d_in[11];
  const float* ba2  = (const float*)d_in[12];
  const float* Wc1  = (const float*)d_in[13];
  const float* bc1  = (const float*)d_in[14];
  const float* Wc2  = (const float*)d_in[15];
  const float* bc2  = (const float*)d_in[16];
  float* out = (float*)d_out;
  float* ws = (float*)d_ws;

  hipLaunchKernelGGL(k_prep, dim3(2304), dim3(256), 0, stream, W_ih, W_hh, Wa1, Wc1, ws);
  hipLaunchKernelGGL(k_pemb, dim3(625), dim3(1024), 0, stream, graph_emb, b_ih, b_hh, ws);
  hipLaunchKernelGGL(k_aemb, dim3(625), dim3(256), 0, stream, graph_emb, ws);
  hipLaunchKernelGGL(k_lstm, dim3(32), dim3(512), 0, stream, paths, path_lens, ws);
  hipLaunchKernelGGL(k_critic, dim3(512), dim3(256), 0, stream, bc1, Wc2, bc2, out, ws);
  hipLaunchKernelGGL(k_actor, dim3(512), dim3(256), 0, stream, neighbors, n_nb, ba1, Wa2, ba2, out, ws);
}

// Round 5
// 898.585 us; speedup vs baseline: 6.6686x; 1.2970x over previous
//
#include <hip/hip_runtime.h>
#include <math.h>

#define NV 10000
#define B 512
#define L 256
#define E 64

typedef _Float16 f16;
typedef _Float16 f16x4 __attribute__((ext_vector_type(4)));
typedef _Float16 f16x8 __attribute__((ext_vector_type(8)));
typedef float f32x4 __attribute__((ext_vector_type(4)));

// ws layout (f32 offsets)
#define OFF_WA1HT 0u         // [256][256] f32  Wa1hT[k*256+j] = Wa1[j*512+k]
#define OFF_WC1T  65536u     // [256][256] f32
#define OFF_WB    131072u    // 262144 B: fp8 frags of 8*W_hh  [((w*4+q)*8+kt)*64+lane]*8+j
#define OFF_WIHF  196608u    // 262144 f16: frags of W_ih (same mapping)
#define OFF_WA1NF 327680u    // 65536 f16: frags of Wa1n  [(w*8+kt)*512+lane*8+j]
#define OFF_PEMB  360448u    // 10,240,000 f16: P_perm[v][hc*4+q] = 128*(ge@W_ih^T+b)[v][q*256+hc]
#define OFF_AEMB  5480448u   // 2,560,000 f16: A_emb[v][256]
#define OFF_HBUF  6760448u   // [512][256] f32 h_final
// total 6,891,520 f32 = 27.6 MB

__device__ __forceinline__ int fp8_byte(float x) {
  return __builtin_amdgcn_cvt_pk_fp8_f32(x, x, 0, false) & 0xFF;
}
__device__ __forceinline__ float fp8_dec(int b) {
  return __builtin_amdgcn_cvt_f32_fp8(b, 0);
}

__global__ __launch_bounds__(256) void k_prep(
    const float* __restrict__ W_ih, const float* __restrict__ W_hh,
    const float* __restrict__ Wa1, const float* __restrict__ Wc1,
    float* __restrict__ ws) {
  int idx = blockIdx.x * 256 + threadIdx.x;
  if (idx < 262144) {  // W_hh fp8 frags (x8) + W_ih f16 frags, shared decomposition
    int j = idx & 7, lane = (idx >> 3) & 63, kt = (idx >> 9) & 7;
    int q = (idx >> 12) & 3, w = (idx >> 14) & 15;
    int n = q * 256 + w * 16 + (lane & 15);
    int k = kt * 32 + (lane >> 4) * 8 + j;
    ((unsigned char*)(ws + OFF_WB))[idx] = (unsigned char)fp8_byte(W_hh[n * 256 + k] * 8.f);
    ((f16*)(ws + OFF_WIHF))[idx] = (f16)W_ih[n * 256 + k];
    return;
  }
  int p = idx - 262144;
  if (p < 65536) {  // Wa1n f16 frags
    int j = p & 7, lane = (p >> 3) & 63, kt = (p >> 9) & 7, w = (p >> 12) & 15;
    int n = w * 16 + (lane & 15);
    int k = kt * 32 + (lane >> 4) * 8 + j;
    ((f16*)(ws + OFF_WA1NF))[p] = (f16)Wa1[n * 512 + 256 + k];
    return;
  }
  int i2 = p - 65536;
  if (i2 < 65536) {  // actor/critic transposes
    int k = i2 >> 8, j = i2 & 255;
    ws[OFF_WA1HT + i2] = Wa1[j * 512 + k];
    ws[OFF_WC1T + i2] = Wc1[j * 256 + k];
  }
}

// Fused P_emb + A_emb via f16 MFMA. 32 vertices/block, 1024 threads (16 waves).
// Wave w: WIH n-tiles {w*4+q}, Wa1n n-tile {w}; 2 row-tiles (M=32).
__global__ __launch_bounds__(1024) void k_pemb(
    const float* __restrict__ ge, const float* __restrict__ b_ih,
    const float* __restrict__ b_hh, float* __restrict__ ws) {
  __shared__ f16 Alds[32 * 264];
  const int tid = threadIdx.x, w = tid >> 6, lane = tid & 63;
  const int l15 = lane & 15, quad = lane >> 4;
  const int vbase = blockIdx.x * 32;
  for (int i = tid; i < 32 * 256; i += 1024) {
    int row = i >> 8, col = i & 255;
    int v = min(vbase + row, NV - 1);
    Alds[row * 264 + col] = (f16)ge[(size_t)v * 256 + col];
  }
  __syncthreads();
  const f16* __restrict__ WIHF = (const f16*)(ws + OFF_WIHF);
  const f16* __restrict__ WANF = (const f16*)(ws + OFF_WA1NF);
  f32x4 Cp[2][4], Ca[2];
#pragma unroll
  for (int t = 0; t < 2; ++t) {
    Ca[t] = (f32x4){0.f, 0.f, 0.f, 0.f};
#pragma unroll
    for (int q = 0; q < 4; ++q) Cp[t][q] = (f32x4){0.f, 0.f, 0.f, 0.f};
  }
#pragma unroll
  for (int kt = 0; kt < 8; ++kt) {
    f16x8 a0 = *(const f16x8*)(Alds + l15 * 264 + kt * 32 + quad * 8);
    f16x8 a1 = *(const f16x8*)(Alds + (l15 + 16) * 264 + kt * 32 + quad * 8);
#pragma unroll
    for (int q = 0; q < 4; ++q) {
      f16x8 bq = *(const f16x8*)(WIHF + (size_t)(((w * 4 + q) * 8 + kt) * 512 + lane * 8));
      Cp[0][q] = __builtin_amdgcn_mfma_f32_16x16x32_f16(a0, bq, Cp[0][q], 0, 0, 0);
      Cp[1][q] = __builtin_amdgcn_mfma_f32_16x16x32_f16(a1, bq, Cp[1][q], 0, 0, 0);
    }
    f16x8 bn = *(const f16x8*)(WANF + (size_t)((w * 8 + kt) * 512 + lane * 8));
    Ca[0] = __builtin_amdgcn_mfma_f32_16x16x32_f16(a0, bn, Ca[0], 0, 0, 0);
    Ca[1] = __builtin_amdgcn_mfma_f32_16x16x32_f16(a1, bn, Ca[1], 0, 0, 0);
  }
  const int hc = w * 16 + l15;
  float bias[4];
#pragma unroll
  for (int q = 0; q < 4; ++q) {
    int n = q * 256 + hc;
    bias[q] = b_ih[n] + b_hh[n];
  }
  f16* __restrict__ P = (f16*)(ws + OFF_PEMB);
  f16* __restrict__ A = (f16*)(ws + OFF_AEMB);
#pragma unroll
  for (int tile = 0; tile < 2; ++tile)
#pragma unroll
    for (int reg = 0; reg < 4; ++reg) {
      int v = vbase + tile * 16 + quad * 4 + reg;
      if (v < NV) {
        f16x4 pw;
#pragma unroll
        for (int q = 0; q < 4; ++q) pw[q] = (f16)(128.f * (Cp[tile][q][reg] + bias[q]));
        *(f16x4*)(P + (size_t)v * 1024 + hc * 4) = pw;
        A[(size_t)v * 256 + hc] = (f16)Ca[tile][reg];
      }
    }
}

// LSTM: 32 blocks x 1024 threads (16 waves, 4/SIMD). W_hh fp8 resident (64 VGPR).
// Wave w owns n-tiles {q*16+w} (q = gate) -> lane updates 4 cells, all gates local.
__global__ __launch_bounds__(1024) void k_lstm(
    const int* __restrict__ paths, const int* __restrict__ path_lens,
    float* __restrict__ ws) {
  const int tid = threadIdx.x, w = tid >> 6, lane = tid & 63;
  const int l15 = lane & 15, quad = lane >> 4;
  const int g16 = blockIdx.x * 16;

  __shared__ char hA[4][16 * 264];  // [parity*2 + hi/lo][p*264 + hc]
  __shared__ int red16[16];
  for (int i = tid; i < 4224; i += 1024) ((int*)hA)[i] = 0;
  if (tid < 16) red16[tid] = path_lens[g16 + tid];
  __syncthreads();
  int lmax = 0;
#pragma unroll
  for (int i = 0; i < 16; ++i) lmax = max(lmax, red16[i]);

  // persistent B-frags (64 VGPR)
  const long* __restrict__ WBl = (const long*)(ws + OFF_WB);
  long Bf[4][8];
#pragma unroll
  for (int q = 0; q < 4; ++q)
#pragma unroll
    for (int kt = 0; kt < 8; ++kt)
      Bf[q][kt] = WBl[(size_t)(((w * 4 + q) * 8 + kt) * 64 + lane)];

  const f16* __restrict__ Pf = (const f16*)(ws + OFF_PEMB);
  const int hc = w * 16 + l15;

  int lenr[4], pb[4], v4[4];
#pragma unroll
  for (int r = 0; r < 4; ++r) {
    lenr[r] = path_lens[g16 + quad * 4 + r];
    pb[r] = (g16 + quad * 4 + r) * L;
    v4[r] = paths[pb[r]];
  }
  f16x4 pv[4];
#pragma unroll
  for (int r = 0; r < 4; ++r)
    pv[r] = *(const f16x4*)(Pf + (size_t)v4[r] * 1024 + hc * 4);

  float cst[4] = {0.f, 0.f, 0.f, 0.f}, hst[4] = {0.f, 0.f, 0.f, 0.f};

  for (int t = 0; t < lmax; ++t) {
    f32x4 Cf[4];
#pragma unroll
    for (int q = 0; q < 4; ++q)
#pragma unroll
      for (int r = 0; r < 4; ++r) Cf[q][r] = (float)pv[r][q];
    const int t1 = min(t + 1, L - 1);
#pragma unroll
    for (int r = 0; r < 4; ++r) v4[r] = paths[pb[r] + t1];

    const char* hi = hA[(t & 1) * 2];
    const char* lo = hA[(t & 1) * 2 + 1];
#pragma unroll
    for (int kt = 0; kt < 8; ++kt) {
      const long ah = *(const long*)(hi + l15 * 264 + kt * 32 + quad * 8);
      const long al = *(const long*)(lo + l15 * 264 + kt * 32 + quad * 8);
#pragma unroll
      for (int q = 0; q < 4; ++q) {
        Cf[q] = __builtin_amdgcn_mfma_f32_16x16x32_fp8_fp8(ah, Bf[q][kt], Cf[q], 0, 0, 0);
        Cf[q] = __builtin_amdgcn_mfma_f32_16x16x32_fp8_fp8(al, Bf[q][kt], Cf[q], 0, 0, 0);
      }
    }
    // prefetch next P (coalesced 8B)
#pragma unroll
    for (int r = 0; r < 4; ++r)
      pv[r] = *(const f16x4*)(Pf + (size_t)v4[r] * 1024 + hc * 4);

    char* nhi = hA[((t + 1) & 1) * 2];
    char* nlo = hA[((t + 1) & 1) * 2 + 1];
    const float inv = 1.f / 128.f;
#pragma unroll
    for (int r = 0; r < 4; ++r) {
      if (t < lenr[r]) {
        const float gi = Cf[0][r] * inv, gf = Cf[1][r] * inv;
        const float gg = Cf[2][r] * inv, go = Cf[3][r] * inv;
        const float si = __builtin_amdgcn_rcpf(1.f + __expf(-gi));
        const float sf = __builtin_amdgcn_rcpf(1.f + __expf(-gf));
        const float so = __builtin_amdgcn_rcpf(1.f + __expf(-go));
        const float tg = 1.f - 2.f * __builtin_amdgcn_rcpf(__expf(2.f * gg) + 1.f);
        const float cn = sf * cst[r] + si * tg;
        cst[r] = cn;
        hst[r] = so * (1.f - 2.f * __builtin_amdgcn_rcpf(__expf(2.f * cn) + 1.f));
      }
      const float s16 = 16.f * hst[r];
      const int hb = fp8_byte(s16);
      const int lb = fp8_byte(s16 - fp8_dec(hb));
      const int p = quad * 4 + r;
      nhi[p * 264 + hc] = (char)hb;
      nlo[p * 264 + hc] = (char)lb;
    }
    __syncthreads();
  }

  float* __restrict__ hbuf = ws + OFF_HBUF;
#pragma unroll
  for (int r = 0; r < 4; ++r)
    hbuf[(g16 + quad * 4 + r) * 256 + hc] = hst[r];
}

// fused critic + actor heads: one block per path
__global__ __launch_bounds__(256) void k_head(
    const int* __restrict__ neighbors, const int* __restrict__ n_nb,
    const float* __restrict__ ba1, const float* __restrict__ Wa2,
    const float* __restrict__ ba2, const float* __restrict__ bc1,
    const float* __restrict__ Wc2, const float* __restrict__ bc2,
    float* __restrict__ out, const float* __restrict__ ws) {
  __shared__ float hs[256];
  __shared__ float u[256];
  __shared__ float red[256];
  __shared__ float logits[64];
  const float* __restrict__ Wa1hT = ws + OFF_WA1HT;
  const float* __restrict__ Wc1T = ws + OFF_WC1T;
  const f16* __restrict__ A = (const f16*)(ws + OFF_AEMB);
  const float* __restrict__ hbuf = ws + OFF_HBUF;
  const int b = blockIdx.x, j = threadIdx.x;
  hs[j] = hbuf[b * 256 + j];
  __syncthreads();
  float acc = ba1[j], ch = bc1[j];
  for (int k = 0; k < 256; ++k) {
    const float hk = hs[k];
    acc += Wa1hT[k * 256 + j] * hk;
    ch += Wc1T[k * 256 + j] * hk;
  }
  u[j] = acc;
  ch = ch > 0.f ? ch : expm1f(ch);
  red[j] = ch * Wc2[j];
  __syncthreads();
  for (int s = 128; s > 0; s >>= 1) {
    if (j < s) red[j] += red[j + s];
    __syncthreads();
  }
  if (j == 0) out[B * E + b] = red[0] + bc2[0];

  const int wave = j >> 6, lane = j & 63;
  const float ba2v = ba2[0];
  for (int e = wave; e < 64; e += 4) {
    const int v = neighbors[b * 64 + e];
    float s = 0.f;
#pragma unroll
    for (int m = 0; m < 4; ++m) {
      const int jj = lane + 64 * m;
      float a = u[jj] + (float)A[(size_t)v * 256 + jj];
      a = a > 0.f ? a : expm1f(a);
      s += a * Wa2[jj];
    }
#pragma unroll
    for (int d = 32; d > 0; d >>= 1) s += __shfl_xor(s, d, 64);
    if (lane == 0) logits[e] = s + ba2v;
  }
  __syncthreads();
  if (j < 64) {
    const int ne = n_nb[b];
    const bool valid = j < ne;
    float le = valid ? logits[j] : -1e30f;
    float m = le;
#pragma unroll
    for (int d = 32; d > 0; d >>= 1) m = fmaxf(m, __shfl_xor(m, d, 64));
    float p = valid ? expf(le - m) : 0.f;
    float sm = p;
#pragma unroll
    for (int d = 32; d > 0; d >>= 1) sm += __shfl_xor(sm, d, 64);
    out[b * 64 + j] = p / sm;
  }
}

extern "C" void kernel_launch(void* const* d_in, const int* in_sizes, int n_in,
                              void* d_out, int out_size, void* d_ws, size_t ws_size,
                              hipStream_t stream) {
  (void)in_sizes; (void)n_in; (void)out_size; (void)ws_size;
  const float* graph_emb = (const float*)d_in[0];
  const int* paths       = (const int*)d_in[1];
  const int* path_lens   = (const int*)d_in[2];
  const int* neighbors   = (const int*)d_in[3];
  const int* n_nb        = (const int*)d_in[4];
  const float* W_ih = (const float*)d_in[5];
  const float* W_hh = (const float*)d_in[6];
  const float* b_ih = (const float*)d_in[7];
  const float* b_hh = (const float*)d_in[8];
  const float* Wa1  = (const float*)d_in[9];
  const float* ba1  = (const float*)d_in[10];
  const float* Wa2  = (const float*)d_in[11];
  const float* ba2  = (const float*)d_in[12];
  const float* Wc1  = (const float*)d_in[13];
  const float* bc1  = (const float*)d_in[14];
  const float* Wc2  = (const float*)d_in[15];
  const float* bc2  = (const float*)d_in[16];
  float* out = (float*)d_out;
  float* ws = (float*)d_ws;

  hipLaunchKernelGGL(k_prep, dim3(1536), dim3(256), 0, stream, W_ih, W_hh, Wa1, Wc1, ws);
  hipLaunchKernelGGL(k_pemb, dim3(313), dim3(1024), 0, stream, graph_emb, b_ih, b_hh, ws);
  hipLaunchKernelGGL(k_lstm, dim3(32), dim3(1024), 0, stream, paths, path_lens, ws);
  hipLaunchKernelGGL(k_head, dim3(512), dim3(256), 0, stream, neighbors, n_nb,
                     ba1, Wa2, ba2, bc1, Wc2, bc2, out, ws);
}

// Round 6
// 667.295 us; speedup vs baseline: 8.9800x; 1.3466x over previous
//
#include <hip/hip_runtime.h>
#include <math.h>

#define NV 10000
#define B 512
#define L 256
#define E 64

typedef _Float16 f16;
typedef _Float16 f16x4 __attribute__((ext_vector_type(4)));
typedef _Float16 f16x8 __attribute__((ext_vector_type(8)));
typedef float f32x4 __attribute__((ext_vector_type(4)));

// ws layout (f32 offsets)
#define OFF_WA1HT 0u         // [256][256] f32  Wa1hT[k*256+j] = Wa1[j*512+k]
#define OFF_WC1T  65536u     // [256][256] f32
#define OFF_WB    131072u    // 262144 B: fp8 frags of 8*W_hh  [((w*4+q)*8+kt)*64+lane]*8+j
#define OFF_WIHF  196608u    // 262144 f16: frags of W_ih (same mapping)
#define OFF_WA1NF 327680u    // 65536 f16: frags of Wa1n  [(w*8+kt)*512+lane*8+j]
#define OFF_PEMB  360448u    // 10,240,000 f16: P_perm[v][hc*4+q] = 128*(ge@W_ih^T+b)[v][q*256+hc]
#define OFF_AEMB  5480448u   // 2,560,000 f16: A_emb[v][256]
#define OFF_HBUF  6760448u   // [512][256] f32 h_final
// total 6,891,520 f32 = 27.6 MB

__device__ __forceinline__ int fp8_byte(float x) {
  return __builtin_amdgcn_cvt_pk_fp8_f32(x, x, 0, false) & 0xFF;
}
__device__ __forceinline__ float fp8_dec(int b) {
  return __builtin_amdgcn_cvt_f32_fp8(b, 0);
}

__global__ __launch_bounds__(256) void k_prep(
    const float* __restrict__ W_ih, const float* __restrict__ W_hh,
    const float* __restrict__ Wa1, const float* __restrict__ Wc1,
    float* __restrict__ ws) {
  int idx = blockIdx.x * 256 + threadIdx.x;
  if (idx < 262144) {  // W_hh fp8 frags (x8) + W_ih f16 frags, shared decomposition
    int j = idx & 7, lane = (idx >> 3) & 63, kt = (idx >> 9) & 7;
    int q = (idx >> 12) & 3, w = (idx >> 14) & 15;
    int n = q * 256 + w * 16 + (lane & 15);
    int k = kt * 32 + (lane >> 4) * 8 + j;
    ((unsigned char*)(ws + OFF_WB))[idx] = (unsigned char)fp8_byte(W_hh[n * 256 + k] * 8.f);
    ((f16*)(ws + OFF_WIHF))[idx] = (f16)W_ih[n * 256 + k];
    return;
  }
  int p = idx - 262144;
  if (p < 65536) {  // Wa1n f16 frags
    int j = p & 7, lane = (p >> 3) & 63, kt = (p >> 9) & 7, w = (p >> 12) & 15;
    int n = w * 16 + (lane & 15);
    int k = kt * 32 + (lane >> 4) * 8 + j;
    ((f16*)(ws + OFF_WA1NF))[p] = (f16)Wa1[n * 512 + 256 + k];
    return;
  }
  int i2 = p - 65536;
  if (i2 < 65536) {  // actor/critic transposes
    int k = i2 >> 8, j = i2 & 255;
    ws[OFF_WA1HT + i2] = Wa1[j * 512 + k];
    ws[OFF_WC1T + i2] = Wc1[j * 256 + k];
  }
}

// Fused P_emb + A_emb via f16 MFMA. 32 vertices/block, 1024 threads (16 waves).
__global__ __launch_bounds__(1024) void k_pemb(
    const float* __restrict__ ge, const float* __restrict__ b_ih,
    const float* __restrict__ b_hh, float* __restrict__ ws) {
  __shared__ f16 Alds[32 * 264];
  const int tid = threadIdx.x, w = tid >> 6, lane = tid & 63;
  const int l15 = lane & 15, quad = lane >> 4;
  const int vbase = blockIdx.x * 32;
  for (int i = tid; i < 32 * 256; i += 1024) {
    int row = i >> 8, col = i & 255;
    int v = min(vbase + row, NV - 1);
    Alds[row * 264 + col] = (f16)ge[(size_t)v * 256 + col];
  }
  __syncthreads();
  const f16* __restrict__ WIHF = (const f16*)(ws + OFF_WIHF);
  const f16* __restrict__ WANF = (const f16*)(ws + OFF_WA1NF);
  f32x4 Cp[2][4], Ca[2];
#pragma unroll
  for (int t = 0; t < 2; ++t) {
    Ca[t] = (f32x4){0.f, 0.f, 0.f, 0.f};
#pragma unroll
    for (int q = 0; q < 4; ++q) Cp[t][q] = (f32x4){0.f, 0.f, 0.f, 0.f};
  }
#pragma unroll
  for (int kt = 0; kt < 8; ++kt) {
    f16x8 a0 = *(const f16x8*)(Alds + l15 * 264 + kt * 32 + quad * 8);
    f16x8 a1 = *(const f16x8*)(Alds + (l15 + 16) * 264 + kt * 32 + quad * 8);
#pragma unroll
    for (int q = 0; q < 4; ++q) {
      f16x8 bq = *(const f16x8*)(WIHF + (size_t)(((w * 4 + q) * 8 + kt) * 512 + lane * 8));
      Cp[0][q] = __builtin_amdgcn_mfma_f32_16x16x32_f16(a0, bq, Cp[0][q], 0, 0, 0);
      Cp[1][q] = __builtin_amdgcn_mfma_f32_16x16x32_f16(a1, bq, Cp[1][q], 0, 0, 0);
    }
    f16x8 bn = *(const f16x8*)(WANF + (size_t)((w * 8 + kt) * 512 + lane * 8));
    Ca[0] = __builtin_amdgcn_mfma_f32_16x16x32_f16(a0, bn, Ca[0], 0, 0, 0);
    Ca[1] = __builtin_amdgcn_mfma_f32_16x16x32_f16(a1, bn, Ca[1], 0, 0, 0);
  }
  const int hc = w * 16 + l15;
  float bias[4];
#pragma unroll
  for (int q = 0; q < 4; ++q) {
    int n = q * 256 + hc;
    bias[q] = b_ih[n] + b_hh[n];
  }
  f16* __restrict__ P = (f16*)(ws + OFF_PEMB);
  f16* __restrict__ A = (f16*)(ws + OFF_AEMB);
#pragma unroll
  for (int tile = 0; tile < 2; ++tile)
#pragma unroll
    for (int reg = 0; reg < 4; ++reg) {
      int v = vbase + tile * 16 + quad * 4 + reg;
      if (v < NV) {
        f16x4 pw;
#pragma unroll
        for (int q = 0; q < 4; ++q) pw[q] = (f16)(128.f * (Cp[tile][q][reg] + bias[q]));
        *(f16x4*)(P + (size_t)v * 1024 + hc * 4) = pw;
        A[(size_t)v * 256 + hc] = (f16)Ca[tile][reg];
      }
    }
}

// LSTM: 64 blocks x 1024 threads, G=8 paths/block.
// A rows 0-7 = fp8-hi(16h) of paths 0-7; rows 8-15 = fp8 residual plane.
// One K=256 pass computes both; gates recovered via shfl_xor(32) + add.
__global__ __launch_bounds__(1024) void k_lstm(
    const int* __restrict__ paths, const int* __restrict__ path_lens,
    float* __restrict__ ws) {
  const int tid = threadIdx.x, w = tid >> 6, lane = tid & 63;
  const int l15 = lane & 15, quad = lane >> 4;
  const int g8 = blockIdx.x * 8;

  __shared__ char hA[2][16 * 264];  // [parity][row*264 + k]; rows 0-7 hi, 8-15 lo
  __shared__ int red8[8];
  for (int i = tid; i < 2112; i += 1024) ((int*)hA)[i] = 0;
  if (tid < 8) red8[tid] = path_lens[g8 + tid];
  __syncthreads();
  int lmax = 0;
#pragma unroll
  for (int i = 0; i < 8; ++i) lmax = max(lmax, red8[i]);

  // persistent B-frags: wave w -> n = q*256 + w*16 + l15 (all 4 gates of h-block w)
  const long* __restrict__ WBl = (const long*)(ws + OFF_WB);
  long Bf[4][8];
#pragma unroll
  for (int q = 0; q < 4; ++q)
#pragma unroll
    for (int kt = 0; kt < 8; ++kt)
      Bf[q][kt] = WBl[(size_t)(((w * 4 + q) * 8 + kt) * 64 + lane)];

  const f16* __restrict__ Pf = (const f16*)(ws + OFF_PEMB);
  const int hc = w * 16 + l15;
  const bool ldr = quad < 2;  // quads 0,1 gather P (hi rows); quads 2,3 init 0

  int pb[4], v4[4];
  f16x4 pv[4];
  if (ldr) {
#pragma unroll
    for (int r = 0; r < 4; ++r) {
      pb[r] = (g8 + quad * 4 + r) * L;
      v4[r] = paths[pb[r]];
    }
#pragma unroll
    for (int r = 0; r < 4; ++r)
      pv[r] = *(const f16x4*)(Pf + (size_t)v4[r] * 1024 + hc * 4);
  }

  // cell ownership: quads {0,2} -> paths 0-3, {1,3} -> paths 4-7; quad bit1 picks reg pair
  const int pbase = (quad & 1) * 4;
  const int rsel = (quad >> 1) * 2;       // 0 or 2
  const int p0 = pbase + rsel, p1 = p0 + 1;
  const int len0 = red8[p0], len1 = red8[p1];
  float c0 = 0.f, c1 = 0.f, h0 = 0.f, h1 = 0.f;
  __syncthreads();

  for (int t = 0; t < lmax; ++t) {
    f32x4 Cf[4];
    if (ldr) {
#pragma unroll
      for (int q = 0; q < 4; ++q)
#pragma unroll
        for (int r = 0; r < 4; ++r) Cf[q][r] = (float)pv[r][q];
    } else {
#pragma unroll
      for (int q = 0; q < 4; ++q) Cf[q] = (f32x4){0.f, 0.f, 0.f, 0.f};
    }
    const int t1 = min(t + 1, L - 1);
    if (ldr) {
#pragma unroll
      for (int r = 0; r < 4; ++r) v4[r] = paths[pb[r] + t1];
    }
    const char* hp = hA[t & 1];
#pragma unroll
    for (int kt = 0; kt < 8; ++kt) {
      const long a = *(const long*)(hp + l15 * 264 + kt * 32 + quad * 8);
#pragma unroll
      for (int q = 0; q < 4; ++q)
        Cf[q] = __builtin_amdgcn_mfma_f32_16x16x32_fp8_fp8(a, Bf[q][kt], Cf[q], 0, 0, 0);
    }
    if (ldr) {
#pragma unroll
      for (int r = 0; r < 4; ++r)
        pv[r] = *(const f16x4*)(Pf + (size_t)v4[r] * 1024 + hc * 4);
    }
    // combine hi+lo across quad partners; select this lane's two cells
    float G0[4], G1[4];
#pragma unroll
    for (int q = 0; q < 4; ++q) {
      const float a0 = Cf[q][0] + __shfl_xor(Cf[q][0], 32, 64);
      const float a1 = Cf[q][1] + __shfl_xor(Cf[q][1], 32, 64);
      const float a2 = Cf[q][2] + __shfl_xor(Cf[q][2], 32, 64);
      const float a3 = Cf[q][3] + __shfl_xor(Cf[q][3], 32, 64);
      G0[q] = rsel ? a2 : a0;
      G1[q] = rsel ? a3 : a1;
    }
    char* nh = hA[(t + 1) & 1];
    const float inv = 1.f / 128.f;
    if (t < len0) {
      const float si = __builtin_amdgcn_rcpf(1.f + __expf(-G0[0] * inv));
      const float sf = __builtin_amdgcn_rcpf(1.f + __expf(-G0[1] * inv));
      const float tg = 1.f - 2.f * __builtin_amdgcn_rcpf(__expf(2.f * G0[2] * inv) + 1.f);
      const float so = __builtin_amdgcn_rcpf(1.f + __expf(-G0[3] * inv));
      c0 = sf * c0 + si * tg;
      h0 = so * (1.f - 2.f * __builtin_amdgcn_rcpf(__expf(2.f * c0) + 1.f));
    }
    if (t < len1) {
      const float si = __builtin_amdgcn_rcpf(1.f + __expf(-G1[0] * inv));
      const float sf = __builtin_amdgcn_rcpf(1.f + __expf(-G1[1] * inv));
      const float tg = 1.f - 2.f * __builtin_amdgcn_rcpf(__expf(2.f * G1[2] * inv) + 1.f);
      const float so = __builtin_amdgcn_rcpf(1.f + __expf(-G1[3] * inv));
      c1 = sf * c1 + si * tg;
      h1 = so * (1.f - 2.f * __builtin_amdgcn_rcpf(__expf(2.f * c1) + 1.f));
    }
    {
      const float s0 = 16.f * h0;
      const int hb0 = fp8_byte(s0);
      nh[p0 * 264 + hc] = (char)hb0;
      nh[(p0 + 8) * 264 + hc] = (char)fp8_byte(s0 - fp8_dec(hb0));
      const float s1 = 16.f * h1;
      const int hb1 = fp8_byte(s1);
      nh[p1 * 264 + hc] = (char)hb1;
      nh[(p1 + 8) * 264 + hc] = (char)fp8_byte(s1 - fp8_dec(hb1));
    }
    __syncthreads();
  }

  float* __restrict__ hbuf = ws + OFF_HBUF;
  hbuf[(g8 + p0) * 256 + hc] = h0;
  hbuf[(g8 + p1) * 256 + hc] = h1;
}

// fused critic + actor heads: one block per path
__global__ __launch_bounds__(256) void k_head(
    const int* __restrict__ neighbors, const int* __restrict__ n_nb,
    const float* __restrict__ ba1, const float* __restrict__ Wa2,
    const float* __restrict__ ba2, const float* __restrict__ bc1,
    const float* __restrict__ Wc2, const float* __restrict__ bc2,
    float* __restrict__ out, const float* __restrict__ ws) {
  __shared__ float hs[256];
  __shared__ float u[256];
  __shared__ float red[256];
  __shared__ float logits[64];
  const float* __restrict__ Wa1hT = ws + OFF_WA1HT;
  const float* __restrict__ Wc1T = ws + OFF_WC1T;
  const f16* __restrict__ A = (const f16*)(ws + OFF_AEMB);
  const float* __restrict__ hbuf = ws + OFF_HBUF;
  const int b = blockIdx.x, j = threadIdx.x;
  hs[j] = hbuf[b * 256 + j];
  __syncthreads();
  float acc = ba1[j], ch = bc1[j];
  for (int k = 0; k < 256; ++k) {
    const float hk = hs[k];
    acc += Wa1hT[k * 256 + j] * hk;
    ch += Wc1T[k * 256 + j] * hk;
  }
  u[j] = acc;
  ch = ch > 0.f ? ch : expm1f(ch);
  red[j] = ch * Wc2[j];
  __syncthreads();
  for (int s = 128; s > 0; s >>= 1) {
    if (j < s) red[j] += red[j + s];
    __syncthreads();
  }
  if (j == 0) out[B * E + b] = red[0] + bc2[0];

  const int wave = j >> 6, lane = j & 63;
  const float ba2v = ba2[0];
  for (int e = wave; e < 64; e += 4) {
    const int v = neighbors[b * 64 + e];
    float s = 0.f;
#pragma unroll
    for (int m = 0; m < 4; ++m) {
      const int jj = lane + 64 * m;
      float a = u[jj] + (float)A[(size_t)v * 256 + jj];
      a = a > 0.f ? a : expm1f(a);
      s += a * Wa2[jj];
    }
#pragma unroll
    for (int d = 32; d > 0; d >>= 1) s += __shfl_xor(s, d, 64);
    if (lane == 0) logits[e] = s + ba2v;
  }
  __syncthreads();
  if (j < 64) {
    const int ne = n_nb[b];
    const bool valid = j < ne;
    float le = valid ? logits[j] : -1e30f;
    float m = le;
#pragma unroll
    for (int d = 32; d > 0; d >>= 1) m = fmaxf(m, __shfl_xor(m, d, 64));
    float p = valid ? expf(le - m) : 0.f;
    float sm = p;
#pragma unroll
    for (int d = 32; d > 0; d >>= 1) sm += __shfl_xor(sm, d, 64);
    out[b * 64 + j] = p / sm;
  }
}

extern "C" void kernel_launch(void* const* d_in, const int* in_sizes, int n_in,
                              void* d_out, int out_size, void* d_ws, size_t ws_size,
                              hipStream_t stream) {
  (void)in_sizes; (void)n_in; (void)out_size; (void)ws_size;
  const float* graph_emb = (const float*)d_in[0];
  const int* paths       = (const int*)d_in[1];
  const int* path_lens   = (const int*)d_in[2];
  const int* neighbors   = (const int*)d_in[3];
  const int* n_nb        = (const int*)d_in[4];
  const float* W_ih = (const float*)d_in[5];
  const float* W_hh = (const float*)d_in[6];
  const float* b_ih = (const float*)d_in[7];
  const float* b_hh = (const float*)d_in[8];
  const float* Wa1  = (const float*)d_in[9];
  const float* ba1  = (const float*)d_in[10];
  const float* Wa2  = (const float*)d_in[11];
  const float* ba2  = (const float*)d_in[12];
  const float* Wc1  = (const float*)d_in[13];
  const float* bc1  = (const float*)d_in[14];
  const float* Wc2  = (const float*)d_in[15];
  const float* bc2  = (const float*)d_in[16];
  float* out = (float*)d_out;
  float* ws = (float*)d_ws;

  hipLaunchKernelGGL(k_prep, dim3(1536), dim3(256), 0, stream, W_ih, W_hh, Wa1, Wc1, ws);
  hipLaunchKernelGGL(k_pemb, dim3(313), dim3(1024), 0, stream, graph_emb, b_ih, b_hh, ws);
  hipLaunchKernelGGL(k_lstm, dim3(64), dim3(1024), 0, stream, paths, path_lens, ws);
  hipLaunchKernelGGL(k_head, dim3(512), dim3(256), 0, stream, neighbors, n_nb,
                     ba1, Wa2, ba2, bc1, Wc2, bc2, out, ws);
}

// Round 7
// 616.858 us; speedup vs baseline: 9.7142x; 1.0818x over previous
//
#include <hip/hip_runtime.h>
#include <math.h>

#define NV 10000
#define B 512
#define L 256
#define E 64

typedef _Float16 f16;
typedef _Float16 f16x8 __attribute__((ext_vector_type(8)));
typedef float f32x4 __attribute__((ext_vector_type(4)));
typedef int v8i __attribute__((ext_vector_type(8)));

// ws layout (f32 offsets)
#define OFF_WA1HT 0u         // [256][256] f32  Wa1hT[k*256+j] = Wa1[j*512+k]
#define OFF_WC1T  65536u     // [256][256] f32
#define OFF_WB    131072u    // 262144 B: fp8 frags of 8*W_hh for mfma_scale 16x16x128
#define OFF_WIHF  196608u    // 262144 f16: frags of W_ih (16x16x32 f16 layout)
#define OFF_WA1NF 327680u    // 65536 f16: frags of Wa1n
#define OFF_PEMB  360448u    // 10,240,000 f32: P_perm[v][hc*4+q] = 128*(ge@W_ih^T+b)[v][q*256+hc]
#define OFF_AEMB  10600448u  // 2,560,000 f16: A_emb[v][256]
// total 11,880,448 f32 = 47.5 MB

__device__ __forceinline__ int fp8_byte(float x) {
  return __builtin_amdgcn_cvt_pk_fp8_f32(x, x, 0, false) & 0xFF;
}
__device__ __forceinline__ unsigned int fp8_pk(float x, float y) {
  return (unsigned int)__builtin_amdgcn_cvt_pk_fp8_f32(x, y, 0, false);
}

#define MFMA_SC(a, b, c) \
  __builtin_amdgcn_mfma_scale_f32_16x16x128_f8f6f4((a), (b), (c), 0, 0, 0, 127, 0, 127)

__global__ __launch_bounds__(256) void k_prep(
    const float* __restrict__ W_ih, const float* __restrict__ W_hh,
    const float* __restrict__ Wa1, const float* __restrict__ Wc1,
    float* __restrict__ ws) {
  int idx = blockIdx.x * 256 + threadIdx.x;
  if (idx < 65536) {  // W_hh fp8 frags (x8) for 16x16x128: dword idx
    int d = idx & 7, lane = (idx >> 3) & 63, kt = (idx >> 9) & 1;
    int q = (idx >> 10) & 3, w = (idx >> 12) & 15;
    int l15 = lane & 15, quad = lane >> 4;
    int n = q * 256 + w * 16 + l15;
    int kb = kt * 128 + quad * 32 + d * 4;
    unsigned int word = 0;
#pragma unroll
    for (int jb = 0; jb < 4; ++jb)
      word |= ((unsigned int)fp8_byte(W_hh[n * 256 + kb + jb] * 8.f)) << (8 * jb);
    ((unsigned int*)(ws + OFF_WB))[idx] = word;
    return;
  }
  int p1 = idx - 65536;
  if (p1 < 262144) {  // W_ih f16 frags (16x16x32 layout, for k_pemb)
    int j = p1 & 7, lane = (p1 >> 3) & 63, kt = (p1 >> 9) & 7;
    int q = (p1 >> 12) & 3, w = (p1 >> 14) & 15;
    int n = q * 256 + w * 16 + (lane & 15);
    int k = kt * 32 + (lane >> 4) * 8 + j;
    ((f16*)(ws + OFF_WIHF))[p1] = (f16)W_ih[n * 256 + k];
    return;
  }
  int p2 = p1 - 262144;
  if (p2 < 65536) {  // Wa1n f16 frags
    int j = p2 & 7, lane = (p2 >> 3) & 63, kt = (p2 >> 9) & 7, w = (p2 >> 12) & 15;
    int n = w * 16 + (lane & 15);
    int k = kt * 32 + (lane >> 4) * 8 + j;
    ((f16*)(ws + OFF_WA1NF))[p2] = (f16)Wa1[n * 512 + 256 + k];
    return;
  }
  int i2 = p2 - 65536;
  if (i2 < 65536) {  // actor/critic transposes
    int k = i2 >> 8, j = i2 & 255;
    ws[OFF_WA1HT + i2] = Wa1[j * 512 + k];
    ws[OFF_WC1T + i2] = Wc1[j * 256 + k];
  }
}

// Fused P_emb + A_emb via f16 MFMA. 32 vertices/block, 1024 threads.
__global__ __launch_bounds__(1024) void k_pemb(
    const float* __restrict__ ge, const float* __restrict__ b_ih,
    const float* __restrict__ b_hh, float* __restrict__ ws) {
  __shared__ f16 Alds[32 * 264];
  const int tid = threadIdx.x, w = tid >> 6, lane = tid & 63;
  const int l15 = lane & 15, quad = lane >> 4;
  const int vbase = blockIdx.x * 32;
  for (int i = tid; i < 32 * 256; i += 1024) {
    int row = i >> 8, col = i & 255;
    int v = min(vbase + row, NV - 1);
    Alds[row * 264 + col] = (f16)ge[(size_t)v * 256 + col];
  }
  __syncthreads();
  const f16* __restrict__ WIHF = (const f16*)(ws + OFF_WIHF);
  const f16* __restrict__ WANF = (const f16*)(ws + OFF_WA1NF);
  f32x4 Cp[2][4], Ca[2];
#pragma unroll
  for (int t = 0; t < 2; ++t) {
    Ca[t] = (f32x4){0.f, 0.f, 0.f, 0.f};
#pragma unroll
    for (int q = 0; q < 4; ++q) Cp[t][q] = (f32x4){0.f, 0.f, 0.f, 0.f};
  }
#pragma unroll
  for (int kt = 0; kt < 8; ++kt) {
    f16x8 a0 = *(const f16x8*)(Alds + l15 * 264 + kt * 32 + quad * 8);
    f16x8 a1 = *(const f16x8*)(Alds + (l15 + 16) * 264 + kt * 32 + quad * 8);
#pragma unroll
    for (int q = 0; q < 4; ++q) {
      f16x8 bq = *(const f16x8*)(WIHF + (size_t)(((w * 4 + q) * 8 + kt) * 512 + lane * 8));
      Cp[0][q] = __builtin_amdgcn_mfma_f32_16x16x32_f16(a0, bq, Cp[0][q], 0, 0, 0);
      Cp[1][q] = __builtin_amdgcn_mfma_f32_16x16x32_f16(a1, bq, Cp[1][q], 0, 0, 0);
    }
    f16x8 bn = *(const f16x8*)(WANF + (size_t)((w * 8 + kt) * 512 + lane * 8));
    Ca[0] = __builtin_amdgcn_mfma_f32_16x16x32_f16(a0, bn, Ca[0], 0, 0, 0);
    Ca[1] = __builtin_amdgcn_mfma_f32_16x16x32_f16(a1, bn, Ca[1], 0, 0, 0);
  }
  const int hc = w * 16 + l15;
  float bias[4];
#pragma unroll
  for (int q = 0; q < 4; ++q) {
    int n = q * 256 + hc;
    bias[q] = b_ih[n] + b_hh[n];
  }
  float* __restrict__ P = ws + OFF_PEMB;
  f16* __restrict__ A = (f16*)(ws + OFF_AEMB);
#pragma unroll
  for (int tile = 0; tile < 2; ++tile)
#pragma unroll
    for (int reg = 0; reg < 4; ++reg) {
      int v = vbase + tile * 16 + quad * 4 + reg;
      if (v < NV) {
        f32x4 pw;
#pragma unroll
        for (int q = 0; q < 4; ++q) pw[q] = 128.f * (Cp[tile][q][reg] + bias[q]);
        *(f32x4*)(P + (size_t)v * 1024 + hc * 4) = pw;
        A[(size_t)v * 256 + hc] = (f16)Ca[tile][reg];
      }
    }
}

// LSTM + fused heads: 64 blocks x 1024 threads, G=8 paths/block.
// hA rows 0-7 = fp8(16h) hi of paths 0-7; rows 8-15 = fp8 residual. Both C-row
// groups init with 0.5*P (uniform, no divergence); combine reconstructs P + h.W.
__global__ __launch_bounds__(1024) void k_lstm(
    const int* __restrict__ paths, const int* __restrict__ path_lens,
    const int* __restrict__ neighbors, const int* __restrict__ n_nb,
    const float* __restrict__ ba1, const float* __restrict__ Wa2,
    const float* __restrict__ ba2, const float* __restrict__ bc1,
    const float* __restrict__ Wc2, const float* __restrict__ bc2,
    float* __restrict__ out, float* __restrict__ ws) {
  const int tid = threadIdx.x, w = tid >> 6, lane = tid & 63;
  const int l15 = lane & 15, quad = lane >> 4;
  const int g8 = blockIdx.x * 8;

  __shared__ char hA[2][16 * 272];   // [parity][row*272 + k] fp8
  __shared__ int red8[8];
  __shared__ float hfin[8][257];
  __shared__ float u_s[8][256];
  __shared__ float part_s[8][64][2];
  __shared__ float vred[8][132];

  for (int i = tid; i < 2 * 16 * 272 / 4; i += 1024) ((int*)hA)[i] = 0;
  if (tid < 8) red8[tid] = path_lens[g8 + tid];
  __syncthreads();
  int lmax = 0;
#pragma unroll
  for (int i = 0; i < 8; ++i) lmax = max(lmax, red8[i]);

  // persistent B-frags for mfma_scale 16x16x128 (64 VGPR)
  const v8i* __restrict__ WBv = (const v8i*)(ws + OFF_WB);
  v8i Bf[4][2];
#pragma unroll
  for (int q = 0; q < 4; ++q)
#pragma unroll
    for (int kt = 0; kt < 2; ++kt)
      Bf[q][kt] = WBv[(size_t)(((w * 4 + q) * 2 + kt) * 64 + lane)];

  const float* __restrict__ Pf = ws + OFF_PEMB;
  const int hc = w * 16 + l15;

  // lane's C rows: quad*4+r (r=0..3); path of row = row&7. All lanes load P.
  int prow[4], v4[4];
#pragma unroll
  for (int r = 0; r < 4; ++r) {
    prow[r] = (quad * 4 + r) & 7;
    v4[r] = paths[(g8 + prow[r]) * L];
  }
  f32x4 pv[4];
#pragma unroll
  for (int r = 0; r < 4; ++r)
    pv[r] = *(const f32x4*)(Pf + (size_t)v4[r] * 1024 + hc * 4);

  // cell ownership (as R6, verified): p0,p1
  const int rsel = (quad >> 1) * 2;
  const int p0 = (quad & 1) * 4 + rsel, p1 = p0 + 1;
  const int len0 = red8[p0], len1 = red8[p1];
  float c0 = 0.f, c1 = 0.f, h0 = 0.f, h1 = 0.f;
  __syncthreads();

  for (int t = 0; t < lmax; ++t) {
    f32x4 Cf[4];
#pragma unroll
    for (int q = 0; q < 4; ++q)
#pragma unroll
      for (int r = 0; r < 4; ++r) Cf[q][r] = 0.5f * pv[r][q];
    const int t1 = min(t + 1, L - 1);
#pragma unroll
    for (int r = 0; r < 4; ++r) v4[r] = paths[(g8 + prow[r]) * L + t1];

    const char* hp = hA[t & 1];
#pragma unroll
    for (int kt = 0; kt < 2; ++kt) {
      const v8i a = *(const v8i*)(hp + l15 * 272 + kt * 128 + quad * 32);
#pragma unroll
      for (int q = 0; q < 4; ++q) Cf[q] = MFMA_SC(a, Bf[q][kt], Cf[q]);
    }
    // prefetch next P
#pragma unroll
    for (int r = 0; r < 4; ++r)
      pv[r] = *(const f32x4*)(Pf + (size_t)v4[r] * 1024 + hc * 4);

    // combine hi+lo across quad partners; select this lane's two cells
    float G0[4], G1[4];
#pragma unroll
    for (int q = 0; q < 4; ++q) {
      const float a0 = Cf[q][0] + __shfl_xor(Cf[q][0], 32, 64);
      const float a1 = Cf[q][1] + __shfl_xor(Cf[q][1], 32, 64);
      const float a2 = Cf[q][2] + __shfl_xor(Cf[q][2], 32, 64);
      const float a3 = Cf[q][3] + __shfl_xor(Cf[q][3], 32, 64);
      G0[q] = rsel ? a2 : a0;
      G1[q] = rsel ? a3 : a1;
    }
    char* nh = hA[(t + 1) & 1];
    const float inv = 1.f / 128.f;
    if (t < len0) {
      const float si = __builtin_amdgcn_rcpf(1.f + __expf(-G0[0] * inv));
      const float sf = __builtin_amdgcn_rcpf(1.f + __expf(-G0[1] * inv));
      const float tg = 1.f - 2.f * __builtin_amdgcn_rcpf(__expf(2.f * G0[2] * inv) + 1.f);
      const float so = __builtin_amdgcn_rcpf(1.f + __expf(-G0[3] * inv));
      c0 = sf * c0 + si * tg;
      h0 = so * (1.f - 2.f * __builtin_amdgcn_rcpf(__expf(2.f * c0) + 1.f));
    }
    if (t < len1) {
      const float si = __builtin_amdgcn_rcpf(1.f + __expf(-G1[0] * inv));
      const float sf = __builtin_amdgcn_rcpf(1.f + __expf(-G1[1] * inv));
      const float tg = 1.f - 2.f * __builtin_amdgcn_rcpf(__expf(2.f * G1[2] * inv) + 1.f);
      const float so = __builtin_amdgcn_rcpf(1.f + __expf(-G1[3] * inv));
      c1 = sf * c1 + si * tg;
      h1 = so * (1.f - 2.f * __builtin_amdgcn_rcpf(__expf(2.f * c1) + 1.f));
    }
    {
      const unsigned int hp2 = fp8_pk(16.f * h0, 16.f * h1);
      const float d0 = __builtin_amdgcn_cvt_f32_fp8((int)hp2, 0);
      const float d1 = __builtin_amdgcn_cvt_f32_fp8((int)hp2, 1);
      const unsigned int lp2 = fp8_pk(16.f * h0 - d0, 16.f * h1 - d1);
      nh[p0 * 272 + hc] = (char)(hp2 & 0xFF);
      nh[p1 * 272 + hc] = (char)((hp2 >> 8) & 0xFF);
      nh[(p0 + 8) * 272 + hc] = (char)(lp2 & 0xFF);
      nh[(p1 + 8) * 272 + hc] = (char)((lp2 >> 8) & 0xFF);
    }
    __syncthreads();
  }

  // ---- fused heads for this block's 8 paths ----
  hfin[p0][hc] = h0;
  hfin[p1][hc] = h1;
  __syncthreads();

  const float* __restrict__ Wa1hT = ws + OFF_WA1HT;
  const float* __restrict__ Wc1T = ws + OFF_WC1T;
  const int p = tid >> 7, jj = tid & 127;
  float aa0 = ba1[jj], aa1 = ba1[jj + 128];
  float cc0 = bc1[jj], cc1 = bc1[jj + 128];
  for (int k = 0; k < 256; ++k) {
    const float hk = hfin[p][k];
    aa0 += Wa1hT[k * 256 + jj] * hk;
    aa1 += Wa1hT[k * 256 + jj + 128] * hk;
    cc0 += Wc1T[k * 256 + jj] * hk;
    cc1 += Wc1T[k * 256 + jj + 128] * hk;
  }
  u_s[p][jj] = aa0;
  u_s[p][jj + 128] = aa1;
  cc0 = cc0 > 0.f ? cc0 : expm1f(cc0);
  cc1 = cc1 > 0.f ? cc1 : expm1f(cc1);
  vred[p][jj] = cc0 * Wc2[jj] + cc1 * Wc2[jj + 128];
  __syncthreads();
  if (tid < 512) {
    const int pp = tid >> 6, lp = tid & 63;
    float s = vred[pp][lp] + vred[pp][lp + 64];
#pragma unroll
    for (int d = 32; d > 0; d >>= 1) s += __shfl_xor(s, d, 64);
    if (lp == 0) out[B * E + g8 + pp] = s + bc2[0];
  }
  // actor logits
  const f16* __restrict__ A = (const f16*)(ws + OFF_AEMB);
  const int e = tid & 63, jh = (tid >> 6) & 1;
  const int nbv = neighbors[(g8 + p) * 64 + e];
  float s = 0.f;
  const int jb = jh * 128;
  for (int j2 = 0; j2 < 128; ++j2) {
    const int j = jb + j2;
    float a = u_s[p][j] + (float)A[(size_t)nbv * 256 + j];
    a = a > 0.f ? a : expm1f(a);
    s += a * Wa2[j];
  }
  part_s[p][e][jh] = s;
  __syncthreads();
  if (tid < 512) {
    const int pp = tid >> 6, ee = tid & 63;
    const int ne = n_nb[g8 + pp];
    const bool valid = ee < ne;
    float le = valid ? (part_s[pp][ee][0] + part_s[pp][ee][1] + ba2[0]) : -1e30f;
    float m = le;
#pragma unroll
    for (int d = 32; d > 0; d >>= 1) m = fmaxf(m, __shfl_xor(m, d, 64));
    float pe = valid ? __expf(le - m) : 0.f;
    float sm = pe;
#pragma unroll
    for (int d = 32; d > 0; d >>= 1) sm += __shfl_xor(sm, d, 64);
    out[(g8 + pp) * 64 + ee] = pe / sm;
  }
}

extern "C" void kernel_launch(void* const* d_in, const int* in_sizes, int n_in,
                              void* d_out, int out_size, void* d_ws, size_t ws_size,
                              hipStream_t stream) {
  (void)in_sizes; (void)n_in; (void)out_size; (void)ws_size;
  const float* graph_emb = (const float*)d_in[0];
  const int* paths       = (const int*)d_in[1];
  const int* path_lens   = (const int*)d_in[2];
  const int* neighbors   = (const int*)d_in[3];
  const int* n_nb        = (const int*)d_in[4];
  const float* W_ih = (const float*)d_in[5];
  const float* W_hh = (const float*)d_in[6];
  const float* b_ih = (const float*)d_in[7];
  const float* b_hh = (const float*)d_in[8];
  const float* Wa1  = (const float*)d_in[9];
  const float* ba1  = (const float*)d_in[10];
  const float* Wa2  = (const float*)d_in[11];
  const float* ba2  = (const float*)d_in[12];
  const float* Wc1  = (const float*)d_in[13];
  const float* bc1  = (const float*)d_in[14];
  const float* Wc2  = (const float*)d_in[15];
  const float* bc2  = (const float*)d_in[16];
  float* out = (float*)d_out;
  float* ws = (float*)d_ws;

  hipLaunchKernelGGL(k_prep, dim3(1792), dim3(256), 0, stream, W_ih, W_hh, Wa1, Wc1, ws);
  hipLaunchKernelGGL(k_pemb, dim3(313), dim3(1024), 0, stream, graph_emb, b_ih, b_hh, ws);
  hipLaunchKernelGGL(k_lstm, dim3(64), dim3(1024), 0, stream, paths, path_lens,
                     neighbors, n_nb, ba1, Wa2, ba2, bc1, Wc2, bc2, out, ws);
}